// Round 15
// baseline (228.949 us; speedup 1.0000x reference)
//
#include <hip/hip_runtime.h>
#include <math.h>

#define D 256
#define K 1024
#define NR 65536
#define ST_SIZE (NR * D)          // 16777216
#define LOSS_OFF ST_SIZE
#define IDX_OFF (ST_SIZE + 1)
#define BM 32
#define TPB 256
#define NBLK (NR / BM)            // 2048
#define MARGIN 2e-3f
#define CAND_CAP 2048

typedef short bf16x8 __attribute__((ext_vector_type(8)));
typedef float f32x16 __attribute__((ext_vector_type(16)));

// f32 -> bf16 RNE (bit-level)
__device__ __forceinline__ unsigned f2bf(float f) {
    unsigned u = __float_as_uint(f);
    return (u + 0x7FFFu + ((u >> 16) & 1u)) >> 16;
}
__device__ __forceinline__ uint4 packB(float4 a, float4 b) {
    uint4 w;
    w.x = f2bf(-2.f * a.x) | (f2bf(-2.f * a.y) << 16);
    w.y = f2bf(-2.f * a.z) | (f2bf(-2.f * a.w) << 16);
    w.z = f2bf(-2.f * b.x) | (f2bf(-2.f * b.y) << 16);
    w.w = f2bf(-2.f * b.z) | (f2bf(-2.f * b.w) << 16);
    return w;
}

// monotone float<->uint key (scores can be negative)
__device__ __forceinline__ unsigned fkey(float f) {
    unsigned b = __float_as_uint(f);
    return (b & 0x80000000u) ? ~b : (b | 0x80000000u);
}
__device__ __forceinline__ float finv(unsigned u) {
    unsigned b = (u & 0x80000000u) ? (u ^ 0x80000000u) : ~u;
    return __uint_as_float(b);
}

// anti-contraction square (numpy-identical rounding: mul rounded alone)
__device__ __forceinline__ float sq_nf(float x) {
    float s = x * x;
    asm volatile("" : "+v"(s));
    return s;
}
// numpy pairwise sum of squares over 256 elements (bit-exact, validated r2-r14)
template <typename F>
__device__ __forceinline__ float np_sumsq256(F ld) {
    float tot[2];
    #pragma unroll
    for (int h = 0; h < 2; ++h) {
        const int base = h * 128;
        float r[8];
        #pragma unroll
        for (int j = 0; j < 8; ++j) r[j] = sq_nf(ld(base + j));
        for (int i = 8; i < 128; i += 8) {
            #pragma unroll
            for (int j = 0; j < 8; ++j) r[j] += sq_nf(ld(base + i + j));
        }
        tot[h] = ((r[0] + r[1]) + (r[2] + r[3])) + ((r[4] + r[5]) + (r[6] + r[7]));
    }
    return tot[0] + tot[1];
}

// prep: blocks 0..127 pack bf16(-2e) in MFMA fragment order; blocks 128..131 se
__global__ void prep_kernel(const float* __restrict__ emb,
                            unsigned short* __restrict__ pb,
                            float* __restrict__ se) {
    if (blockIdx.x < 128) {
        const int c  = blockIdx.x * 256 + threadIdx.x;    // chunk id, 32768 total
        const int cg = c >> 10, r = c & 1023;
        const int ks = r >> 6,  l = r & 63;
        const float4* s4 = (const float4*)(emb + (size_t)(cg * 32 + (l & 31)) * D
                                               + ks * 16 + (l >> 5) * 8);
        ((uint4*)pb)[c] = packB(s4[0], s4[1]);
    } else {
        const int k = (blockIdx.x - 128) * 256 + threadIdx.x;   // < 1024
        const float* row = emb + (size_t)k * D;
        se[k] = np_sumsq256([&](int i) { return row[i]; });
    }
}

// main: BM=32, col-split waves, barrier-free B-streaming sweep,
//       filtered exact rescore (x from LDS) + st(=q) + loss(=bestd)
__global__ __launch_bounds__(TPB, 3)
void vq_main(const float* __restrict__ inp, const float* __restrict__ emb,
             const unsigned short* __restrict__ pb, const float* __restrict__ se,
             float* __restrict__ out, double* __restrict__ lsum) {
    __shared__ __align__(16) float xs[BM][260];            // 33.3 KB, live all kernel
    __shared__ float sx_s[BM];
    __shared__ unsigned rfink[BM];                         // fkey of approx row-min
    __shared__ unsigned cand[CAND_CAP];                    // 8 KB
    __shared__ float candsc[CAND_CAP];                     // 8 KB  (~50.2 KB tot)
    __shared__ unsigned bestd[BM];
    __shared__ unsigned bestc[BM];
    __shared__ int ncand;

    const int t   = threadIdx.x;
    const int ws  = t >> 6;      // wave 0..3: owns cgs {ws, ws+4, ..., ws+28}
    const int l   = t & 63;
    const int col = l & 31;
    const int hi  = l >> 5;
    const int r0  = blockIdx.x * BM;

    if (t < BM) { bestd[t] = 0xFFFFFFFFu; bestc[t] = 0xFFFFFFFFu; rfink[t] = 0xFFFFFFFFu; }
    if (t == 0) ncand = 0;

    // ---- stage X tile coalesced (once; xs persists for afr/sx/rescore) ----
    {
        const float4* inq = (const float4*)(inp + (size_t)r0 * D);
        #pragma unroll
        for (int i = 0; i < (BM * D) / (4 * TPB); ++i) {   // 8 iters
            const int e = i * TPB + t;
            *(float4*)&xs[e >> 6][(e & 63) * 4] = inq[e];
        }
    }
    __syncthreads();                             // xs + inits published

    // ---- A fragments from LDS: rows col (all waves same 32 rows) ----
    bf16x8 afr[16];
    #pragma unroll
    for (int ks = 0; ks < 16; ++ks) {
        float4 a = *(const float4*)&xs[col][ks * 16 + hi * 8];
        float4 b = *(const float4*)&xs[col][ks * 16 + hi * 8 + 4];
        bf16x8 v;
        v[0] = (short)f2bf(a.x); v[1] = (short)f2bf(a.y);
        v[2] = (short)f2bf(a.z); v[3] = (short)f2bf(a.w);
        v[4] = (short)f2bf(b.x); v[5] = (short)f2bf(b.y);
        v[6] = (short)f2bf(b.z); v[7] = (short)f2bf(b.w);
        afr[ks] = v;
    }

    // ---- sx from LDS: numpy-pairwise-exact, 16 lanes per row ----
    {
        const int slot = t & 15, grp = t >> 4;   // 16 groups of 16 lanes
        const int j = slot & 7, h = slot >> 3;
        #pragma unroll
        for (int p = 0; p < 2; ++p) {
            const int row = p * 16 + grp;
            const float* base = &xs[row][h * 128 + j];
            float s = sq_nf(base[0]);
            #pragma unroll
            for (int i = 1; i < 16; ++i) s += sq_nf(base[i * 8]);
            #pragma unroll
            for (int m = 1; m <= 8; m <<= 1) s += __shfl_xor(s, m);  // local-left
            if (slot == 0) sx_s[row] = s;
        }
    }

    // ---- barrier-free sweep: wave ws streams its 8 cgs from L2 (pb) ----
    float rmin[16];
    #pragma unroll
    for (int i = 0; i < 16; ++i) rmin[i] = INFINITY;
    const bf16x8* pbf = (const bf16x8*)pb;

    for (int c8 = 0; c8 < 8; ++c8) {
        const int cg = c8 * 4 + ws;
        const float sev = se[cg * 32 + col];     // L1/L2-cached
        f32x16 aE, aO;
        #pragma unroll
        for (int i = 0; i < 16; ++i) { aE[i] = sev; aO[i] = 0.f; }
        const bf16x8* bp = pbf + (size_t)cg * 1024 + l;
        #pragma unroll
        for (int ks = 0; ks < 16; ks += 2) {     // B straight from L2 -> MFMA
            aE = __builtin_amdgcn_mfma_f32_32x32x16_bf16(afr[ks],     bp[ks * 64],       aE, 0, 0, 0);
            aO = __builtin_amdgcn_mfma_f32_32x32x16_bf16(afr[ks + 1], bp[(ks + 1) * 64], aO, 0, 0, 0);
        }
        float sc[16];
        #pragma unroll
        for (int i = 0; i < 16; ++i) sc[i] = aE[i] + aO[i];

        // per-wave running row-min (deterministic, no cross-wave coupling);
        // butterfly every 2nd c8: staleness only raises threshold => superset
        #pragma unroll
        for (int i = 0; i < 16; ++i) rmin[i] = fminf(rmin[i], sc[i]);
        if ((c8 & 1) == 0) {
            #pragma unroll
            for (int i = 0; i < 16; ++i) {
                #pragma unroll
                for (int m = 1; m < 32; m <<= 1)
                    rmin[i] = fminf(rmin[i], __shfl_xor(rmin[i], m));
            }
        }
        #pragma unroll
        for (int i = 0; i < 16; ++i) {
            if (sc[i] <= rmin[i] + MARGIN) {
                const int row_local = (i & 3) + 8 * (i >> 2) + 4 * hi;
                const int p = atomicAdd(&ncand, 1);
                if (p < CAND_CAP) {
                    cand[p]   = ((unsigned)row_local << 10) | (unsigned)(cg * 32 + col);
                    candsc[p] = sc[i];
                }
            }
        }
    }
    // final butterfly; merge per-row approx-min across waves via fkey atomicMin
    #pragma unroll
    for (int i = 0; i < 16; ++i) {
        #pragma unroll
        for (int m = 1; m < 32; m <<= 1)
            rmin[i] = fminf(rmin[i], __shfl_xor(rmin[i], m));
    }
    if (col == 0) {
        #pragma unroll
        for (int i = 0; i < 16; ++i)
            atomicMin(&rfink[(i & 3) + 8 * (i >> 2) + 4 * hi], fkey(rmin[i]));
    }
    __syncthreads();                               // cand list + rfink complete

    // ---- filter + exact f32 rescore: 16 lanes/cand, x from LDS (swizzled) ----
    int n = ncand; if (n > CAND_CAP) n = CAND_CAP;
    {
        const int qw = l >> 4, lq = l & 15;        // quarter-wave, lane-in-quarter
        for (int ci = ws * 4 + qw; ci < n; ci += 16) {
            const unsigned uc = cand[ci];
            const int row_local = uc >> 10, code = uc & 1023;
            const float sc = candsc[ci];
            if (sc <= finv(rfink[row_local]) + MARGIN) {   // survives global-min filter
                const float4* xp = (const float4*)&xs[row_local][0];
                const float4* ep = (const float4*)(emb + (size_t)code * D);
                float p = 0.f;
                #pragma unroll
                for (int q = 0; q < 4; ++q) {      // chunk q*16+lq: LDS conflict-free,
                    float4 x = xp[q * 16 + lq];    // emb coalesced per q
                    float4 e = ep[q * 16 + lq];
                    p = fmaf(x.x, e.x, p);
                    p = fmaf(x.y, e.y, p);
                    p = fmaf(x.z, e.z, p);
                    p = fmaf(x.w, e.w, p);
                }
                #pragma unroll
                for (int m = 1; m <= 8; m <<= 1) p += __shfl_xor(p, m);
                const float tv = sx_s[row_local] + se[code];
                const float d  = fmaf(-2.f, p, tv);    // = fl(t - 2*dot), matches numpy
                if (lq == 0) {
                    candsc[ci] = d;
                    atomicMin(&bestd[row_local], __float_as_uint(d));  // d>0: uint-monotone
                }
            } else if (lq == 0) {
                candsc[ci] = INFINITY;             // can't match bestd in phase 2
            }
        }
    }
    __syncthreads();
    for (int ci = t; ci < n; ci += TPB) {          // tie-break: lowest code at min d
        const unsigned uc = cand[ci];
        if (__float_as_uint(candsc[ci]) == bestd[uc >> 10])
            atomicMin(&bestc[uc >> 10], uc & 1023u);
    }
    __syncthreads();
    if (t < BM) out[IDX_OFF + r0 + t] = (float)bestc[t];

    // ---- st = q (r12-validated): pure q-write, float4 ----
    {
        float4* out4 = (float4*)(out + (size_t)r0 * D);
        const float4* emb4 = (const float4*)emb;
        #pragma unroll
        for (int i = 0; i < (BM * D) / (4 * TPB); ++i) {   // 8 iters
            const int e = i * TPB + t;
            out4[e] = emb4[((size_t)bestc[e >> 6] << 6) + (e & 63)];
        }
    }

    // ---- loss partial: sum of winner distances (bestd) in f64, fixed tree ----
    if (t < BM) {
        double s = (double)__uint_as_float(bestd[t]);
        #pragma unroll
        for (int m = 1; m < 32; m <<= 1) s += __shfl_xor(s, m);
        if (t == 0) lsum[blockIdx.x] = s;
    }
}

// fin: loss = 1.25 * sum(d_winner) / (N*D); one wave, fixed-tree reduction
__global__ void fin_kernel(const double* __restrict__ lsum, float* __restrict__ out) {
    const int l = threadIdx.x;                     // 64 lanes
    double s = 0.0;
    #pragma unroll
    for (int i = 0; i < NBLK / 64; ++i) s += lsum[l * (NBLK / 64) + i];
    #pragma unroll
    for (int m = 1; m < 64; m <<= 1) s += __shfl_xor(s, m);
    if (l == 0) out[LOSS_OFF] = (float)(1.25 * s / (double)ST_SIZE);
}

extern "C" void kernel_launch(void* const* d_in, const int* in_sizes, int n_in,
                              void* d_out, int out_size, void* d_ws, size_t ws_size,
                              hipStream_t stream) {
    const float* inp = (const float*)d_in[0];
    const float* emb = (const float*)d_in[1];
    float* out = (float*)d_out;
    unsigned short* pb = (unsigned short*)d_ws;               // 512 KB (frag-ordered bf16)
    float*  se_ws      = (float*)((char*)d_ws + 524288);      //   4 KB
    double* lsum       = (double*)((char*)d_ws + 528384);     //  16 KB (2048 doubles)

    prep_kernel<<<132, 256, 0, stream>>>(emb, pb, se_ws);
    vq_main<<<NBLK, TPB, 0, stream>>>(inp, emb, pb, se_ws, out, lsum);
    fin_kernel<<<1, 64, 0, stream>>>(lsum, out);
}